// Round 1
// 200.009 us; speedup vs baseline: 1.1404x; 1.1404x over previous
//
#include <hip/hip_runtime.h>

// CompGraphConv round 10: scatter_edges rewritten as block-local LDS binning.
//
// Round-9 scatter_edges (57 us, 10.6% HBM, VALU 1%) was bound by 1.2M
// device-scope atomicAdds (+ their ~32B RMW write traffic: WRITE_SIZE 42.5MB
// vs 4.8MB useful) and 4B scattered stores. New scheme: each block owns a
// 4096-edge chunk, LDS-histograms the coarse buckets, reserves each bucket's
// run with ONE global atomicAdd per (block,bucket) (~229K total, 5x fewer),
// then scatters via LDS cursors into contiguous per-bucket runs (~21B runs ->
// L2 line combining works). Edge entries stay in registers between phases.
// bucket_sort reads a single dense segment per bucket (XCD sub-slots removed
// -- they only existed to tame per-edge atomic contention).

#define DF 64
#define BCAP 2560           // entries per bucket: mean 1534, +26 sigma
#define CPAD 16             // ints per cursor (one 64B line each)
#define NBMAX 1024          // max coarse buckets (NB = ceil(2N/256) = 782)
#define SCHUNK 4096         // edges per scatter block
typedef _Float16 f16;
typedef f16 f16x8 __attribute__((ext_vector_type(8)));
typedef f16 f16x4 __attribute__((ext_vector_type(4)));
typedef f16 f16x2 __attribute__((ext_vector_type(2)));
typedef float f32x4 __attribute__((ext_vector_type(4)));

// y = x - r into A rows (and compact ytab); W_{S,O,I} -> f16 Wf.
__global__ __launch_bounds__(256) void prep_dense(const float* __restrict__ x,
                                                  const float* __restrict__ r,
                                                  f16* __restrict__ A,
                                                  f16* __restrict__ ytab,
                                                  const float* __restrict__ W_S,
                                                  const float* __restrict__ W_O,
                                                  const float* __restrict__ W_I,
                                                  f16* __restrict__ Wf, int N) {
    int t = blockIdx.x * 256 + threadIdx.x;
    int ny = N * 32;                      // f16x2 pairs of y
    if (t < ny) {
        int v = t >> 5, k = (t & 31) * 2;
        float y0 = x[(size_t)v * DF + k]     - r[k];
        float y1 = x[(size_t)v * DF + k + 1] - r[k + 1];
        f16x2 p = {(f16)y0, (f16)y1};
        *(f16x2*)(A + (size_t)v * 192 + k) = p;
        if (ytab) *(f16x2*)(ytab + (size_t)v * 64 + k) = p;
    }
    if (t < 6144) {                       // 3*4096 weight elems as pairs
        int w = t / 2048;
        int i = (t % 2048) * 2;
        const float* W = (w == 0) ? W_S : (w == 1) ? W_O : W_I;
        f16x2 p = {(f16)W[i], (f16)W[i + 1]};
        *(f16x2*)(Wf + w * 4096 + i) = p;
    }
}

// Block-local LDS binning: one 4096-edge chunk per block. Phase A: LDS
// histogram over coarse buckets (entries kept in registers). Phase B: one
// global atomicAdd per touched bucket reserves a contiguous run. Phase C:
// LDS cursors place each entry; contiguous per-bucket runs -> coalescing
// in L2 instead of 1.2M isolated 4B stores + 1.2M global RMWs.
__global__ __launch_bounds__(512) void scatter_edges(const int* __restrict__ src,
                                                     const int* __restrict__ dst,
                                                     int* __restrict__ cur,
                                                     unsigned int* __restrict__ pairBuf,
                                                     int E, int half, int NB) {
    __shared__ int cnt[NBMAX];            // histogram, then reused as cursor
    int t = threadIdx.x;
    int e0 = blockIdx.x * SCHUNK;
    int n = E - e0; if (n > SCHUNK) n = SCHUNK;
    for (int k = t; k < NBMAX; k += 512) cnt[k] = 0;
    __syncthreads();

    unsigned int ent[SCHUNK / 512];
    int bk[SCHUNK / 512];
    #pragma unroll
    for (int i = 0; i < SCHUNK / 512; i++) {
        int idx = t + i * 512;
        bk[i] = -1;
        if (idx < n) {
            int e = e0 + idx;
            int s = __builtin_nontemporal_load(src + e);
            int d = __builtin_nontemporal_load(dst + e);
            int key = (d << 1) | (e >= half ? 1 : 0);
            int b = key >> 8;             // b < NB <= NBMAX (N=100K -> 782)
            ent[i] = (unsigned int)s | ((unsigned int)(key & 255) << 24);
            bk[i] = b;
            atomicAdd(&cnt[b], 1);
        }
    }
    __syncthreads();

    // reserve per-bucket runs; cursor starts at the reserved base
    for (int k = t; k < NB; k += 512) {
        int c = cnt[k];
        cnt[k] = (c > 0) ? atomicAdd(&cur[k * CPAD], c) : 0;
    }
    __syncthreads();

    #pragma unroll
    for (int i = 0; i < SCHUNK / 512; i++) {
        if (bk[i] >= 0) {
            int pos = atomicAdd(&cnt[bk[i]], 1);
            if (pos < BCAP)
                pairBuf[(size_t)bk[i] * BCAP + pos] = ent[i];
        }
    }
}

// Per-bucket LDS counting sort over one dense segment; sorted src written in
// place at the bucket's own region base.
__global__ __launch_bounds__(256) void bucket_sort(unsigned int* __restrict__ pairBuf,
                                                   const int* __restrict__ cur,
                                                   int* __restrict__ deg,
                                                   int* __restrict__ off, int M) {
    __shared__ unsigned int P[2048];
    __shared__ int cnt[256];
    __shared__ int pos[256];
    int b = blockIdx.x;
    int t = threadIdx.x;
    cnt[t] = 0;
    __syncthreads();
    int n = cur[b * CPAD];
    if (n > 2048) n = 2048;               // +13 sigma cap, statistically never
    const unsigned int* seg = pairBuf + (size_t)b * BCAP;
    for (int i = t; i < n; i += 256) {
        unsigned int p = seg[i];
        P[i] = p;
        atomicAdd(&cnt[p >> 24], 1);
    }
    __syncthreads();
    int v = cnt[t];
    pos[t] = v;
    __syncthreads();
    #pragma unroll
    for (int s = 1; s < 256; s <<= 1) {
        int u = (t >= s) ? pos[t - s] : 0;
        __syncthreads();
        pos[t] += u;
        __syncthreads();
    }
    int incl = pos[t];
    int key = (b << 8) + t;
    if (key < M) {
        deg[key] = v;
        off[key] = b * BCAP + incl;      // absolute end; start = end - deg
    }
    __syncthreads();
    pos[t] = incl - v;                   // per-key exclusive cursor
    __syncthreads();
    unsigned int* outb = pairBuf + (size_t)b * BCAP;
    for (int i = t; i < n; i += 256) {
        unsigned int p = P[i];
        int lk = p >> 24;
        int loc = atomicAdd(&pos[lk], 1);
        outb[loc] = p & 0xFFFFFFu;       // dense sorted src, in place
    }
}

// One wave per node pair. Lane = (g, q): g = lane>>4 picks which of 4
// consecutive edges, q = lane&15 picks the k-quad (f16x4). Four packed-f16
// prefix-class accumulators (All, >=t1, >=t2, >=t3); butterfly over g at
// the end; group g stores window g's 8B result.
__global__ __launch_bounds__(256) void gather_sum(const f16* __restrict__ Y,
                                                  int ystride,
                                                  f16* __restrict__ A,
                                                  const int* __restrict__ deg,
                                                  const int* __restrict__ off,
                                                  const unsigned int* __restrict__ srcList,
                                                  int N) {
    int p = (blockIdx.x * 256 + threadIdx.x) >> 6;
    int lane = threadIdx.x & 63;
    int v0 = 2 * p, v1 = 2 * p + 1;
    if (v0 >= N) return;
    const int g = lane >> 4, q = lane & 15;
    bool hasV1 = (v1 < N);
    int dO0 = deg[4 * p], dI0 = deg[4 * p + 1];
    int dO1 = hasV1 ? deg[4 * p + 2] : 0;
    int dI1 = hasV1 ? deg[4 * p + 3] : 0;
    int s = off[4 * p] - dO0;
    int t1 = s + dO0, t2 = t1 + dI0, t3 = t2 + dO1;
    int end = t3 + dI1;

    const f16x2 zz = {(f16)0.f, (f16)0.f};
    f16x2 aA0 = zz, aA1 = zz, a10 = zz, a11 = zz,
          a20 = zz, a21 = zz, a30 = zz, a31 = zz;

    int e = s;
    for (; e + 8 <= end; e += 8) {
        int eA = e + g, eB = e + g + 4;
        int iA = (int)srcList[eA];
        int iB = (int)srcList[eB];
        const f16x2* pa = (const f16x2*)(Y + (size_t)iA * ystride + 4 * q);
        const f16x2* pb = (const f16x2*)(Y + (size_t)iB * ystride + 4 * q);
        f16x2 va0 = pa[0], va1 = pa[1];
        f16x2 vb0 = pb[0], vb1 = pb[1];
        aA0 += va0; aA1 += va1;
        a10 += (eA >= t1) ? va0 : zz;  a11 += (eA >= t1) ? va1 : zz;
        a20 += (eA >= t2) ? va0 : zz;  a21 += (eA >= t2) ? va1 : zz;
        a30 += (eA >= t3) ? va0 : zz;  a31 += (eA >= t3) ? va1 : zz;
        aA0 += vb0; aA1 += vb1;
        a10 += (eB >= t1) ? vb0 : zz;  a11 += (eB >= t1) ? vb1 : zz;
        a20 += (eB >= t2) ? vb0 : zz;  a21 += (eB >= t2) ? vb1 : zz;
        a30 += (eB >= t3) ? vb0 : zz;  a31 += (eB >= t3) ? vb1 : zz;
    }
    if (e < end) {                       // masked tail (wave-uniform branch)
        int eA = e + g, eB = e + g + 4;
        bool inA = (eA < end), inB = (eB < end);
        // OOB reads stay inside the bucket region (end+7 < region cap)
        int iA = inA ? (int)srcList[eA] : 0;
        int iB = inB ? (int)srcList[eB] : 0;
        const f16x2* pa = (const f16x2*)(Y + (size_t)iA * ystride + 4 * q);
        const f16x2* pb = (const f16x2*)(Y + (size_t)iB * ystride + 4 * q);
        f16x2 va0 = pa[0], va1 = pa[1];
        f16x2 vb0 = pb[0], vb1 = pb[1];
        aA0 += inA ? va0 : zz; aA1 += inA ? va1 : zz;
        a10 += (inA && eA >= t1) ? va0 : zz;  a11 += (inA && eA >= t1) ? va1 : zz;
        a20 += (inA && eA >= t2) ? va0 : zz;  a21 += (inA && eA >= t2) ? va1 : zz;
        a30 += (inA && eA >= t3) ? va0 : zz;  a31 += (inA && eA >= t3) ? va1 : zz;
        aA0 += inB ? vb0 : zz; aA1 += inB ? vb1 : zz;
        a10 += (inB && eB >= t1) ? vb0 : zz;  a11 += (inB && eB >= t1) ? vb1 : zz;
        a20 += (inB && eB >= t2) ? vb0 : zz;  a21 += (inB && eB >= t2) ? vb1 : zz;
        a30 += (inB && eB >= t3) ? vb0 : zz;  a31 += (inB && eB >= t3) ? vb1 : zz;
    }

    // butterfly over the 4 groups, on packed dwords (bit-exact shuffles)
    f16x2 acc[8] = {aA0, aA1, a10, a11, a20, a21, a30, a31};
    #pragma unroll
    for (int i = 0; i < 8; i++) {
        int w = __builtin_bit_cast(int, acc[i]);
        f16x2 u16 = __builtin_bit_cast(f16x2, __shfl_xor(w, 16, 64));
        acc[i] += u16;
        w = __builtin_bit_cast(int, acc[i]);
        f16x2 u32 = __builtin_bit_cast(f16x2, __shfl_xor(w, 32, 64));
        acc[i] += u32;
    }
    // window sums (packed): d0=All-G1, d1=G1-G2, d2=G2-G3, d3=G3
    f16x2 d0l = acc[0] - acc[2], d0h = acc[1] - acc[3];
    f16x2 d1l = acc[2] - acc[4], d1h = acc[3] - acc[5];
    f16x2 d2l = acc[4] - acc[6], d2h = acc[5] - acc[7];
    f16x2 d3l = acc[6],          d3h = acc[7];
    f16x2 wl01 = (g == 0) ? d0l : d1l, wh01 = (g == 0) ? d0h : d1h;
    f16x2 wl23 = (g == 2) ? d2l : d3l, wh23 = (g == 2) ? d2h : d3h;
    f16x2 wl = (g < 2) ? wl01 : wl23,  wh = (g < 2) ? wh01 : wh23;

    int vtgt = (g < 2) ? v0 : v1;
    int voff = (g & 1) ? 128 : 64;
    float d01 = (g == 0) ? (float)dO0 : (float)dI0;
    float d23 = (g == 2) ? (float)dO1 : (float)dI1;
    float dd = (g < 2) ? d01 : d23;
    if (vtgt < N) {
        const f16x2* yp = (const f16x2*)(Y + (size_t)vtgt * ystride + 4 * q);
        f16x2 y0 = yp[0], y1 = yp[1];
        f16x4 res;
        res[0] = (f16)((float)wl[0] - dd * (float)y0[0]);
        res[1] = (f16)((float)wl[1] - dd * (float)y0[1]);
        res[2] = (f16)((float)wh[0] - dd * (float)y1[0]);
        res[3] = (f16)((float)wh[1] - dd * (float)y1[1]);
        *(f16x4*)(A + (size_t)vtgt * 192 + voff + 4 * q) = res;
    }
}

// C[N,64] = A[N,192] @ B[192,64] via mfma_f32_16x16x32_f16, A-frags straight
// from global (rows contiguous), B-frags from f16 Wf (L1-broadcast). No LDS.
__global__ __launch_bounds__(256) void gemv_mfma(const f16* __restrict__ A,
                                                 const f16* __restrict__ Wf,
                                                 const int* __restrict__ deg,
                                                 const float* __restrict__ b_O,
                                                 const float* __restrict__ b_I,
                                                 const float* __restrict__ b_S,
                                                 float* __restrict__ out,
                                                 int N, int nTiles) {
    int gw = (blockIdx.x * 256 + threadIdx.x) >> 6;
    int nw = gridDim.x * 4;
    const int lane = threadIdx.x & 63;
    const int mlane = lane & 15;
    const int koff = (lane >> 4) * 8;

    for (int tile = gw; tile < nTiles; tile += nw) {
        const int vbase = tile * 16;
        int va = vbase + mlane; if (va >= N) va = N - 1;
        const f16* arow = A + (size_t)va * 192 + koff;
        f16x8 af[6];
        #pragma unroll
        for (int s = 0; s < 6; s++) af[s] = *(const f16x8*)(arow + s * 32);

        f32x4 accs[4];
        #pragma unroll
        for (int c = 0; c < 4; c++) {
            f32x4 acc = {0.f, 0.f, 0.f, 0.f};
            #pragma unroll
            for (int s = 0; s < 6; s++) {
                int k = s * 32 + koff;
                const f16* bp = Wf + (k >> 6) * 4096 + (c * 16 + mlane) * 64 + (k & 63);
                f16x8 bf = *(const f16x8*)bp;
                acc = __builtin_amdgcn_mfma_f32_16x16x32_f16(af[s], bf, acc, 0, 0, 0);
            }
            accs[c] = acc;
        }

        // C/D layout: col = lane&15, row = (lane>>4)*4 + reg
        const int mrow0 = (lane >> 4) * 4;
        #pragma unroll
        for (int reg = 0; reg < 4; reg++) {
            int v = vbase + mrow0 + reg;
            if (v >= N) continue;
            float cO = (float)deg[2 * v], cI = (float)deg[2 * v + 1];
            #pragma unroll
            for (int c = 0; c < 4; c++) {
                int j = c * 16 + mlane;
                out[(size_t)v * DF + j] = accs[c][reg] + b_S[j] + cO * b_O[j] + cI * b_I[j];
            }
        }
    }
}

__global__ void r_transform(const float* __restrict__ r,
                            const float* __restrict__ W_R,
                            const float* __restrict__ b_R,
                            float* __restrict__ out, int N) {
    int j = threadIdx.x;  // 64 threads
    float s = b_R[j];
    #pragma unroll 16
    for (int k = 0; k < 64; k++) s += r[k] * W_R[j * 64 + k];
    out[(size_t)N * DF + j] = s;
}

extern "C" void kernel_launch(void* const* d_in, const int* in_sizes, int n_in,
                              void* d_out, int out_size, void* d_ws, size_t ws_size,
                              hipStream_t stream) {
    const float* x   = (const float*)d_in[0];
    const float* r   = (const float*)d_in[1];
    const int*   src = (const int*)d_in[2];
    const int*   dst = (const int*)d_in[3];
    const float* W_O = (const float*)d_in[4];
    const float* b_O = (const float*)d_in[5];
    const float* W_I = (const float*)d_in[6];
    const float* b_I = (const float*)d_in[7];
    const float* W_S = (const float*)d_in[8];
    const float* b_S = (const float*)d_in[9];
    const float* W_R = (const float*)d_in[10];
    const float* b_R = (const float*)d_in[11];
    float* out = (float*)d_out;

    const int N = in_sizes[0] / DF;
    const int E = in_sizes[2];
    const int half = E / 2;
    const int M = 2 * N;                 // keys: (dst<<1)|isI
    const int NB = (M + 255) >> 8;       // 256 keys per bucket (NB <= NBMAX)

    // ws: A[N*192] f16 | Wf[3*4096] f16 | deg[2N] | off[2N]
    //     | cur[NB*CPAD] | pairBuf[NB*BCAP] | ytab[N*64] f16 (optional)
    f16* A  = (f16*)d_ws;
    f16* Wf = A + (size_t)N * 192;
    int* deg = (int*)(Wf + 3 * 4096);
    int* off = deg + M;
    int* cur = off + M;
    unsigned int* pairBuf = (unsigned int*)(cur + (size_t)NB * CPAD);
    f16* ytab = (f16*)(pairBuf + (size_t)NB * BCAP);
    size_t need = (size_t)((char*)(ytab + (size_t)N * 64) - (char*)d_ws);
    const bool useYtab = (ws_size >= need);
    f16* ytabArg = useYtab ? ytab : nullptr;
    const f16* Y = useYtab ? ytab : A;
    const int ystride = useYtab ? 64 : 192;

    hipMemsetAsync(cur, 0, (size_t)NB * CPAD * sizeof(int), stream);

    scatter_edges<<<(E + SCHUNK - 1) / SCHUNK, 512, 0, stream>>>(src, dst, cur,
                                                                 pairBuf, E, half, NB);
    int nThread = N * 32;
    prep_dense<<<(nThread + 255) / 256, 256, 0, stream>>>(x, r, A, ytabArg,
                                                          W_S, W_O, W_I, Wf, N);
    bucket_sort<<<NB, 256, 0, stream>>>(pairBuf, cur, deg, off, M);

    int nPairs = (N + 1) / 2;            // one wave per node pair
    int gsBlocks = (nPairs + 3) / 4;
    gather_sum<<<gsBlocks, 256, 0, stream>>>(Y, ystride, A, deg, off, pairBuf, N);

    int nTiles = (N + 15) / 16;
    gemv_mfma<<<1024, 256, 0, stream>>>(A, Wf, deg, b_O, b_I, b_S, out, N, nTiles);
    r_transform<<<1, 64, 0, stream>>>(r, W_R, b_R, out, N);
}

// Round 2
// 186.085 us; speedup vs baseline: 1.2257x; 1.0748x over previous
//
#include <hip/hip_runtime.h>

// CompGraphConv round 11: pipeline fusion 7 -> 4 dispatches.
//
// Round 10 (200 us): all our kernels < 42 us, top dispatches are the
// harness's workspace-poison fills. Remaining cost is structural: 7 serial
// dispatches with gaps, plus a 9.6 MB pairBuf round-trip between
// bucket_sort (writes sorted src to global) and gather_sum (re-reads it).
// Fusions:
//  K1 scatter_prep: edge scatter blocks + dense-prep blocks in ONE grid
//     (scatter = atomic/latency-bound, prep = BW-bound -> co-resident,
//     combined ~ max not sum).
//  K2 sort_gather: per-bucket LDS counting sort keeps the sorted list IN
//     LDS and the same block gathers for its own 128 nodes (src indices via
//     broadcast ds_read). No off[] array, no sorted-list write-back.
//     512 thr = 8 waves x 8 node pairs.
//  K3 gemv_mfma absorbs r_transform (block 0, lanes < 64).

#define DF 64
#define BCAP 2560           // entries per bucket: mean 1534, +26 sigma
#define CPAD 16             // ints per cursor (one 64B line each)
#define NBMAX 1024          // max coarse buckets (NB = ceil(2N/256) = 782)
#define SCHUNK 4096         // edges per scatter block
typedef _Float16 f16;
typedef f16 f16x8 __attribute__((ext_vector_type(8)));
typedef f16 f16x4 __attribute__((ext_vector_type(4)));
typedef f16 f16x2 __attribute__((ext_vector_type(2)));
typedef float f32x4 __attribute__((ext_vector_type(4)));

// K1: blocks [0,SB) = block-local LDS edge binning (round-10 scheme);
//     blocks [SB, SB+PB) = y = x - r (A rows + compact ytab), W -> f16.
__global__ __launch_bounds__(512) void scatter_prep(
    const int* __restrict__ src, const int* __restrict__ dst,
    int* __restrict__ cur, unsigned int* __restrict__ pairBuf,
    int E, int half, int NB, int SB,
    const float* __restrict__ x, const float* __restrict__ r,
    f16* __restrict__ A, f16* __restrict__ ytab,
    const float* __restrict__ W_S, const float* __restrict__ W_O,
    const float* __restrict__ W_I, f16* __restrict__ Wf, int N) {
    int t = threadIdx.x;
    if ((int)blockIdx.x < SB) {
        __shared__ int cnt[NBMAX];        // histogram, then reused as cursor
        int e0 = blockIdx.x * SCHUNK;
        int n = E - e0; if (n > SCHUNK) n = SCHUNK;
        for (int k = t; k < NBMAX; k += 512) cnt[k] = 0;
        __syncthreads();

        unsigned int ent[SCHUNK / 512];
        int bk[SCHUNK / 512];
        #pragma unroll
        for (int i = 0; i < SCHUNK / 512; i++) {
            int idx = t + i * 512;
            bk[i] = -1;
            if (idx < n) {
                int e = e0 + idx;
                int s = __builtin_nontemporal_load(src + e);
                int d = __builtin_nontemporal_load(dst + e);
                int key = (d << 1) | (e >= half ? 1 : 0);
                int b = key >> 8;         // b < NB <= NBMAX
                ent[i] = (unsigned int)s | ((unsigned int)(key & 255) << 24);
                bk[i] = b;
                atomicAdd(&cnt[b], 1);
            }
        }
        __syncthreads();
        // reserve per-bucket runs: ONE global atomic per (block,bucket)
        for (int k = t; k < NB; k += 512) {
            int c = cnt[k];
            cnt[k] = (c > 0) ? atomicAdd(&cur[k * CPAD], c) : 0;
        }
        __syncthreads();
        #pragma unroll
        for (int i = 0; i < SCHUNK / 512; i++) {
            if (bk[i] >= 0) {
                int pos = atomicAdd(&cnt[bk[i]], 1);
                if (pos < BCAP)
                    pairBuf[(size_t)bk[i] * BCAP + pos] = ent[i];
            }
        }
    } else {
        int tt = ((int)blockIdx.x - SB) * 512 + t;
        int ny = N * 32;                  // f16x2 pairs of y
        if (tt < ny) {
            int v = tt >> 5, k = (tt & 31) * 2;
            float y0 = x[(size_t)v * DF + k]     - r[k];
            float y1 = x[(size_t)v * DF + k + 1] - r[k + 1];
            f16x2 p = {(f16)y0, (f16)y1};
            *(f16x2*)(A + (size_t)v * 192 + k) = p;
            if (ytab) *(f16x2*)(ytab + (size_t)v * 64 + k) = p;
        }
        if (tt < 6144) {                  // 3*4096 weight elems as pairs
            int w = tt / 2048;
            int i = (tt % 2048) * 2;
            const float* W = (w == 0) ? W_S : (w == 1) ? W_O : W_I;
            f16x2 p = {(f16)W[i], (f16)W[i + 1]};
            *(f16x2*)(Wf + w * 4096 + i) = p;
        }
    }
}

// K2: per-bucket counting sort (sorted list stays in LDS) + gather for the
// bucket's own 128 nodes. 512 threads = 8 waves x 8 node pairs.
// Lane = (g,q): g = lane>>4 picks 1-of-4 consecutive edges, q = lane&15 the
// k-quad. Four packed-f16 prefix-class accumulators; butterfly over g;
// group g stores window g's 8B result.
__global__ __launch_bounds__(512) void sort_gather(
    unsigned int* __restrict__ pairBuf, const int* __restrict__ cur,
    int* __restrict__ deg,
    const f16* __restrict__ Y, int ystride, f16* __restrict__ A,
    int N, int M) {
    __shared__ unsigned int S[2048 + 8];  // sorted src, +8 zero pad for tail
    __shared__ int cnt[256];
    __shared__ int pos[256];
    int b = blockIdx.x, t = threadIdx.x;
    if (t < 256) cnt[t] = 0;
    __syncthreads();
    int n = cur[b * CPAD];
    if (n > 2048) n = 2048;               // +13 sigma cap, statistically never
    const unsigned int* seg = pairBuf + (size_t)b * BCAP;
    unsigned int ent[4];                  // n<=2048, 512 thr -> <=4 each
    int ne = 0;
    for (int idx = t; idx < n; idx += 512) {
        unsigned int p = seg[idx];
        ent[ne++] = p;
        atomicAdd(&cnt[p >> 24], 1);
    }
    __syncthreads();
    int v = 0, incl = 0;
    if (t < 256) { v = cnt[t]; pos[t] = v; }
    __syncthreads();
    #pragma unroll
    for (int s = 1; s < 256; s <<= 1) {
        int u = 0;
        if (t < 256 && t >= s) u = pos[t - s];
        __syncthreads();
        if (t < 256) pos[t] += u;
        __syncthreads();
    }
    if (t < 256) {
        incl = pos[t];
        int key = (b << 8) + t;
        if (key < M) deg[key] = v;        // gemv bias correction needs this
    }
    __syncthreads();
    if (t < 256) pos[t] = incl - v;       // exclusive cursor for the scatter
    __syncthreads();
    for (int j = 0; j < ne; j++) {
        unsigned int p = ent[j];
        int loc = atomicAdd(&pos[p >> 24], 1);
        S[loc] = p & 0xFFFFFFu;           // dense sorted src, in LDS
    }
    __syncthreads();
    if (t < 8) S[n + t] = 0;              // zero tail pad (n+7 < 2056)
    __syncthreads();
    // after the scatter, pos[l] == inclusive end of run l; base = pos[l]-cnt[l]

    const int wid = t >> 6, lane = t & 63;
    const int g = lane >> 4, q = lane & 15;
    const int vbase = b * 128;
    const f16x2 zz = {(f16)0.f, (f16)0.f};

    for (int i = 0; i < 8; i++) {
        int pp = wid * 8 + i;             // pair index within bucket
        int v0 = vbase + 2 * pp, v1 = v0 + 1;
        if (v0 >= N) break;
        bool hasV1 = (v1 < N);
        int l0 = 4 * pp;
        int dO0 = cnt[l0], dI0 = cnt[l0 + 1];
        int dO1 = hasV1 ? cnt[l0 + 2] : 0;
        int dI1 = hasV1 ? cnt[l0 + 3] : 0;
        int s0 = pos[l0] - dO0;           // base of run l0 (runs contiguous)
        int t1 = s0 + dO0, t2 = t1 + dI0, t3 = t2 + dO1;
        int end = t3 + dI1;

        f16x2 aA0 = zz, aA1 = zz, a10 = zz, a11 = zz,
              a20 = zz, a21 = zz, a30 = zz, a31 = zz;

        int e = s0;
        for (; e + 8 <= end; e += 8) {
            int eA = e + g, eB = e + g + 4;
            int iA = (int)S[eA];
            int iB = (int)S[eB];
            const f16x2* pa = (const f16x2*)(Y + (size_t)iA * ystride + 4 * q);
            const f16x2* pb = (const f16x2*)(Y + (size_t)iB * ystride + 4 * q);
            f16x2 va0 = pa[0], va1 = pa[1];
            f16x2 vb0 = pb[0], vb1 = pb[1];
            aA0 += va0; aA1 += va1;
            a10 += (eA >= t1) ? va0 : zz;  a11 += (eA >= t1) ? va1 : zz;
            a20 += (eA >= t2) ? va0 : zz;  a21 += (eA >= t2) ? va1 : zz;
            a30 += (eA >= t3) ? va0 : zz;  a31 += (eA >= t3) ? va1 : zz;
            aA0 += vb0; aA1 += vb1;
            a10 += (eB >= t1) ? vb0 : zz;  a11 += (eB >= t1) ? vb1 : zz;
            a20 += (eB >= t2) ? vb0 : zz;  a21 += (eB >= t2) ? vb1 : zz;
            a30 += (eB >= t3) ? vb0 : zz;  a31 += (eB >= t3) ? vb1 : zz;
        }
        if (e < end) {                    // masked tail (wave-uniform branch)
            int eA = e + g, eB = e + g + 4;
            bool inA = (eA < end), inB = (eB < end);
            // OOB lanes read the zero pad (eB <= end+6 <= n+6 < 2056)
            int iA = (int)S[eA];
            int iB = (int)S[eB];
            const f16x2* pa = (const f16x2*)(Y + (size_t)iA * ystride + 4 * q);
            const f16x2* pb = (const f16x2*)(Y + (size_t)iB * ystride + 4 * q);
            f16x2 va0 = pa[0], va1 = pa[1];
            f16x2 vb0 = pb[0], vb1 = pb[1];
            aA0 += inA ? va0 : zz; aA1 += inA ? va1 : zz;
            a10 += (inA && eA >= t1) ? va0 : zz;  a11 += (inA && eA >= t1) ? va1 : zz;
            a20 += (inA && eA >= t2) ? va0 : zz;  a21 += (inA && eA >= t2) ? va1 : zz;
            a30 += (inA && eA >= t3) ? va0 : zz;  a31 += (inA && eA >= t3) ? va1 : zz;
            aA0 += inB ? vb0 : zz; aA1 += inB ? vb1 : zz;
            a10 += (inB && eB >= t1) ? vb0 : zz;  a11 += (inB && eB >= t1) ? vb1 : zz;
            a20 += (inB && eB >= t2) ? vb0 : zz;  a21 += (inB && eB >= t2) ? vb1 : zz;
            a30 += (inB && eB >= t3) ? vb0 : zz;  a31 += (inB && eB >= t3) ? vb1 : zz;
        }

        // butterfly over the 4 groups, on packed dwords (bit-exact shuffles)
        f16x2 acc[8] = {aA0, aA1, a10, a11, a20, a21, a30, a31};
        #pragma unroll
        for (int k = 0; k < 8; k++) {
            int w = __builtin_bit_cast(int, acc[k]);
            f16x2 u16 = __builtin_bit_cast(f16x2, __shfl_xor(w, 16, 64));
            acc[k] += u16;
            w = __builtin_bit_cast(int, acc[k]);
            f16x2 u32 = __builtin_bit_cast(f16x2, __shfl_xor(w, 32, 64));
            acc[k] += u32;
        }
        // window sums (packed): d0=All-G1, d1=G1-G2, d2=G2-G3, d3=G3
        f16x2 d0l = acc[0] - acc[2], d0h = acc[1] - acc[3];
        f16x2 d1l = acc[2] - acc[4], d1h = acc[3] - acc[5];
        f16x2 d2l = acc[4] - acc[6], d2h = acc[5] - acc[7];
        f16x2 d3l = acc[6],          d3h = acc[7];
        f16x2 wl01 = (g == 0) ? d0l : d1l, wh01 = (g == 0) ? d0h : d1h;
        f16x2 wl23 = (g == 2) ? d2l : d3l, wh23 = (g == 2) ? d2h : d3h;
        f16x2 wl = (g < 2) ? wl01 : wl23,  wh = (g < 2) ? wh01 : wh23;

        int vtgt = (g < 2) ? v0 : v1;
        int voff = (g & 1) ? 128 : 64;
        float d01 = (g == 0) ? (float)dO0 : (float)dI0;
        float d23 = (g == 2) ? (float)dO1 : (float)dI1;
        float dd = (g < 2) ? d01 : d23;
        if (vtgt < N) {
            const f16x2* yp = (const f16x2*)(Y + (size_t)vtgt * ystride + 4 * q);
            f16x2 y0 = yp[0], y1 = yp[1];
            f16x4 res;
            res[0] = (f16)((float)wl[0] - dd * (float)y0[0]);
            res[1] = (f16)((float)wl[1] - dd * (float)y0[1]);
            res[2] = (f16)((float)wh[0] - dd * (float)y1[0]);
            res[3] = (f16)((float)wh[1] - dd * (float)y1[1]);
            *(f16x4*)(A + (size_t)vtgt * 192 + voff + 4 * q) = res;
        }
    }
}

// K3: C[N,64] = A[N,192] @ B[192,64] via mfma_f32_16x16x32_f16, A-frags
// straight from global, B-frags from f16 Wf (L1-broadcast). No LDS.
// Block 0 lanes <64 also do the r_transform row.
__global__ __launch_bounds__(256) void gemv_mfma(const f16* __restrict__ A,
                                                 const f16* __restrict__ Wf,
                                                 const int* __restrict__ deg,
                                                 const float* __restrict__ b_O,
                                                 const float* __restrict__ b_I,
                                                 const float* __restrict__ b_S,
                                                 const float* __restrict__ r,
                                                 const float* __restrict__ W_R,
                                                 const float* __restrict__ b_R,
                                                 float* __restrict__ out,
                                                 int N, int nTiles) {
    if (blockIdx.x == 0 && threadIdx.x < 64) {
        int j = threadIdx.x;
        float s = b_R[j];
        #pragma unroll 16
        for (int k = 0; k < 64; k++) s += r[k] * W_R[j * 64 + k];
        out[(size_t)N * DF + j] = s;
    }
    int gw = (blockIdx.x * 256 + threadIdx.x) >> 6;
    int nw = gridDim.x * 4;
    const int lane = threadIdx.x & 63;
    const int mlane = lane & 15;
    const int koff = (lane >> 4) * 8;

    for (int tile = gw; tile < nTiles; tile += nw) {
        const int vbase = tile * 16;
        int va = vbase + mlane; if (va >= N) va = N - 1;
        const f16* arow = A + (size_t)va * 192 + koff;
        f16x8 af[6];
        #pragma unroll
        for (int s = 0; s < 6; s++) af[s] = *(const f16x8*)(arow + s * 32);

        f32x4 accs[4];
        #pragma unroll
        for (int c = 0; c < 4; c++) {
            f32x4 acc = {0.f, 0.f, 0.f, 0.f};
            #pragma unroll
            for (int s = 0; s < 6; s++) {
                int k = s * 32 + koff;
                const f16* bp = Wf + (k >> 6) * 4096 + (c * 16 + mlane) * 64 + (k & 63);
                f16x8 bf = *(const f16x8*)bp;
                acc = __builtin_amdgcn_mfma_f32_16x16x32_f16(af[s], bf, acc, 0, 0, 0);
            }
            accs[c] = acc;
        }

        // C/D layout: col = lane&15, row = (lane>>4)*4 + reg
        const int mrow0 = (lane >> 4) * 4;
        #pragma unroll
        for (int reg = 0; reg < 4; reg++) {
            int v = vbase + mrow0 + reg;
            if (v >= N) continue;
            float cO = (float)deg[2 * v], cI = (float)deg[2 * v + 1];
            #pragma unroll
            for (int c = 0; c < 4; c++) {
                int j = c * 16 + mlane;
                out[(size_t)v * DF + j] = accs[c][reg] + b_S[j] + cO * b_O[j] + cI * b_I[j];
            }
        }
    }
}

extern "C" void kernel_launch(void* const* d_in, const int* in_sizes, int n_in,
                              void* d_out, int out_size, void* d_ws, size_t ws_size,
                              hipStream_t stream) {
    const float* x   = (const float*)d_in[0];
    const float* r   = (const float*)d_in[1];
    const int*   src = (const int*)d_in[2];
    const int*   dst = (const int*)d_in[3];
    const float* W_O = (const float*)d_in[4];
    const float* b_O = (const float*)d_in[5];
    const float* W_I = (const float*)d_in[6];
    const float* b_I = (const float*)d_in[7];
    const float* W_S = (const float*)d_in[8];
    const float* b_S = (const float*)d_in[9];
    const float* W_R = (const float*)d_in[10];
    const float* b_R = (const float*)d_in[11];
    float* out = (float*)d_out;

    const int N = in_sizes[0] / DF;
    const int E = in_sizes[2];
    const int half = E / 2;
    const int M = 2 * N;                 // keys: (dst<<1)|isI
    const int NB = (M + 255) >> 8;       // 256 keys per bucket (NB <= NBMAX)

    // ws: A[N*192] f16 | Wf[3*4096] f16 | deg[2N]
    //     | cur[NB*CPAD] | pairBuf[NB*BCAP] | ytab[N*64] f16 (optional)
    f16* A  = (f16*)d_ws;
    f16* Wf = A + (size_t)N * 192;
    int* deg = (int*)(Wf + 3 * 4096);
    int* cur = deg + M;
    unsigned int* pairBuf = (unsigned int*)(cur + (size_t)NB * CPAD);
    f16* ytab = (f16*)(pairBuf + (size_t)NB * BCAP);
    size_t need = (size_t)((char*)(ytab + (size_t)N * 64) - (char*)d_ws);
    const bool useYtab = (ws_size >= need);
    f16* ytabArg = useYtab ? ytab : nullptr;
    const f16* Y = useYtab ? ytab : A;
    const int ystride = useYtab ? 64 : 192;

    hipMemsetAsync(cur, 0, (size_t)NB * CPAD * sizeof(int), stream);

    const int SB = (E + SCHUNK - 1) / SCHUNK;          // scatter blocks
    const int PB = (N * 32 + 511) / 512;               // prep blocks
    scatter_prep<<<SB + PB, 512, 0, stream>>>(src, dst, cur, pairBuf,
                                              E, half, NB, SB,
                                              x, r, A, ytabArg,
                                              W_S, W_O, W_I, Wf, N);

    sort_gather<<<NB, 512, 0, stream>>>(pairBuf, cur, deg, Y, ystride, A, N, M);

    int nTiles = (N + 15) / 16;
    gemv_mfma<<<1024, 256, 0, stream>>>(A, Wf, deg, b_O, b_I, b_S,
                                        r, W_R, b_R, out, N, nTiles);
}